// Round 15
// baseline (366.713 us; speedup 1.0000x reference)
//
#include <hip/hip_runtime.h>

// GATv2 GNN classifier.
// R15: (a) XCD-head affinity swizzle in edge kernels (bid%8 -> XCD heuristic;
// head h confined to 2 XCDs for H=4, 4 for H=2) -> xl compulsory-miss
// replication drops 8x -> 2x per table. R14 showed edge FETCH pinned at the
// 8-XCD replication floor (191MB ~ 8x25.6MB @ 2.7TB/s).
// (b) gemm_slab W-tile register prefetch (hide stage latency; MfmaUtil was 3%).
// (c) dhist folded into scan3b (1 fewer dispatch).
// Rest identical to R14 (best: 322us).

typedef __attribute__((ext_vector_type(8))) short bf16x8;
typedef __attribute__((ext_vector_type(4))) float f32x4;

#define SCAN_BLOCKS 256

__device__ inline unsigned short f2bf(float f) {
    unsigned u = __float_as_uint(f);
    unsigned r = (u + 0x7fff + ((u >> 16) & 1)) >> 16;   // RNE
    return (unsigned short)r;
}

__device__ inline void unpack8(uint4 a, float* d) {
    d[0] = __uint_as_float(a.x << 16); d[1] = __uint_as_float(a.x & 0xffff0000u);
    d[2] = __uint_as_float(a.y << 16); d[3] = __uint_as_float(a.y & 0xffff0000u);
    d[4] = __uint_as_float(a.z << 16); d[5] = __uint_as_float(a.z & 0xffff0000u);
    d[6] = __uint_as_float(a.w << 16); d[7] = __uint_as_float(a.w & 0xffff0000u);
}

// ---------------- prep: zeros + x->bf16 + W transposes + graph bounds -----
__global__ __launch_bounds__(256) void prep_kernel(
    const float* __restrict__ x, const int* __restrict__ batch, int N, int K1,
    unsigned short* __restrict__ xb,
    const float* __restrict__ Wl1, const float* __restrict__ Wr1,
    unsigned short* __restrict__ T1l, unsigned short* __restrict__ T1r,
    const float* __restrict__ Wl2, const float* __restrict__ Wr2,
    unsigned short* __restrict__ T2l, unsigned short* __restrict__ T2r,
    const float* __restrict__ Wl3, const float* __restrict__ Wr3,
    unsigned short* __restrict__ T3l, unsigned short* __restrict__ T3r,
    int* __restrict__ deg, int* __restrict__ bound)
{
    const int gtid = blockIdx.x * 256 + threadIdx.x;
    const int gsz = (int)gridDim.x * 256;

    for (int i = gtid; i < N; i += gsz) deg[i] = 0;

    // graph boundaries: bound[g] = first node n with batch[n] >= g
    for (int n = gtid; n < N; n += gsz) {
        int bn = batch[n];
        int prev = (n == 0) ? -1 : batch[n - 1];
        for (int g = prev + 1; g <= bn; ++g) bound[g] = n;
        if (n == N - 1)
            for (int g = bn + 1; g <= 64; ++g) bound[g] = N;
    }

    {
        int n4 = (N * K1) >> 2;
        for (int i = gtid; i < n4; i += gsz) {
            float4 v = *reinterpret_cast<const float4*>(x + (size_t)i * 4);
            ushort4 o;
            o.x = f2bf(v.x); o.y = f2bf(v.y); o.z = f2bf(v.z); o.w = f2bf(v.w);
            *reinterpret_cast<ushort4*>(xb + (size_t)i * 4) = o;
        }
    }
    for (int id = gtid; id < 147456; id += gsz) {
        const float* W; unsigned short* T; int K, No, idx;
        if (id < 65536) {                    // layer1: 128x256
            K = 128; No = 256; idx = id & 32767;
            W = (id < 32768) ? Wl1 : Wr1; T = (id < 32768) ? T1l : T1r;
        } else if (id < 131072) {            // layer2: 256x128
            int v = id - 65536; K = 256; No = 128; idx = v & 32767;
            W = (v < 32768) ? Wl2 : Wr2; T = (v < 32768) ? T2l : T2r;
        } else {                             // layer3: 128x64
            int v = id - 131072; K = 128; No = 64; idx = v & 8191;
            W = (v < 8192) ? Wl3 : Wr3; T = (v < 8192) ? T3l : T3r;
        }
        int n = idx / K, k = idx - n * K;
        T[idx] = f2bf(W[(size_t)k * No + n]);
    }
}

// ---------------- A-resident slab GEMM (bf16 MFMA, W reg-prefetch) --------
template <int K, int NY>
__global__ __launch_bounds__(256) void gemm_slab(
    const unsigned short* __restrict__ A,     // [M][K] bf16
    const unsigned short* __restrict__ W0, const unsigned short* __restrict__ W1,
    const float* __restrict__ bias0, const float* __restrict__ bias1,
    unsigned short* __restrict__ OutL, unsigned short* __restrict__ OutR,
    int M)
{
    constexpr int CPR = K / 8;                 // 16B chunks per A row
    constexpr int KH  = K / 128;               // k-half tiles per W row
    constexpr int NST = 2 * NY * KH;           // total W stages
    __shared__ __align__(16) char As[64 * K * 2];
    __shared__ __align__(16) char Bs[64 * 128 * 2];   // W stage / C stage

    const int t = threadIdx.x;
    const int lane = t & 63;
    const int wid = t >> 6;
    const int row0 = blockIdx.x * 64;

    #pragma unroll
    for (int i = 0; i < (64 * CPR) / 256; ++i) {
        int c16 = i * 256 + t;
        int r = c16 / CPR, j = c16 % CPR;
        int gr = row0 + r; if (gr > M - 1) gr = M - 1;
        uint4 v = *reinterpret_cast<const uint4*>(A + (size_t)gr * K + j * 8);
        *reinterpret_cast<uint4*>(As + r * (2 * K) + ((j ^ (r & 7)) << 4)) = v;
    }

    const int ra = wid * 16 + (lane & 15);
    const int rowA_byte = ra * (2 * K);

    uint4 wreg[4];
    auto loadW = [&](int s) {
        int z = s / (NY * KH); int rr = s - z * (NY * KH);
        int y = rr / KH; int kh = rr - y * KH;
        const unsigned short* Wt = z ? W1 : W0;
        #pragma unroll
        for (int u = 0; u < 4; ++u) {
            int c = u * 256 + t;
            int n = c >> 4, j = c & 15;
            wreg[u] = *reinterpret_cast<const uint4*>(
                Wt + (size_t)(y * 64 + n) * K + kh * 128 + j * 8);
        }
    };
    loadW(0);

    f32x4 acc[4];
    #pragma unroll
    for (int j = 0; j < 4; ++j) acc[j] = (f32x4){0.f, 0.f, 0.f, 0.f};

    for (int s = 0; s < NST; ++s) {
        int z = s / (NY * KH); int rr = s - z * (NY * KH);
        int y = rr / KH; int kh = rr - y * KH;

        __syncthreads();                // Bs free (prev MFMA/epilogue done)
        #pragma unroll
        for (int u = 0; u < 4; ++u) {
            int c = u * 256 + t;
            int n = c >> 4, j = c & 15;
            *reinterpret_cast<uint4*>(Bs + n * 256 + ((j ^ (n & 7)) << 4)) = wreg[u];
        }
        __syncthreads();
        if (s + 1 < NST) loadW(s + 1);  // prefetch next tile (hidden by MFMA)

        #pragma unroll
        for (int ks = 0; ks < 4; ++ks) {
            int chA = kh * 16 + ks * 4 + (lane >> 4);
            bf16x8 a = *reinterpret_cast<const bf16x8*>(
                As + rowA_byte + ((chA ^ (ra & 7)) << 4));
            #pragma unroll
            for (int j = 0; j < 4; ++j) {
                int nb = j * 16 + (lane & 15);
                int chB = ks * 4 + (lane >> 4);
                bf16x8 b = *reinterpret_cast<const bf16x8*>(
                    Bs + nb * 256 + ((chB ^ (nb & 7)) << 4));
                acc[j] = __builtin_amdgcn_mfma_f32_16x16x32_bf16(a, b, acc[j], 0, 0, 0);
            }
        }

        if (kh == KH - 1) {
            unsigned short* Out = z ? OutR : OutL;
            const float* bias = z ? bias1 : bias0;
            __syncthreads();            // MFMA Bs reads done
            #pragma unroll
            for (int j = 0; j < 4; ++j) {
                float bb = bias[y * 64 + j * 16 + (lane & 15)];
                #pragma unroll
                for (int q = 0; q < 4; ++q) {
                    int r = wid * 16 + (lane >> 4) * 4 + q;
                    int c = j * 16 + (lane & 15);
                    *reinterpret_cast<unsigned short*>(Bs + r * 128 + c * 2)
                        = f2bf(acc[j][q] + bb);
                }
                acc[j] = (f32x4){0.f, 0.f, 0.f, 0.f};
            }
            __syncthreads();
            int r = t >> 2, ch = t & 3;
            int gr = row0 + r;
            if (gr < M) {
                const uint4* src = reinterpret_cast<const uint4*>(Bs + r * 128 + ch * 32);
                uint4 v0 = src[0], v1 = src[1];
                uint4* dst = reinterpret_cast<uint4*>(
                    Out + ((size_t)y * M + gr) * 64 + ch * 16);
                dst[0] = v0; dst[1] = v1;
            }
        }
    }
}

// ---------------- CSR build ------------------------------------------------
__global__ void hist_kernel(const int* __restrict__ ei, int E, int Etot,
                            int* __restrict__ deg)
{
    int i = blockIdx.x * blockDim.x + threadIdx.x;
    if (i >= Etot) return;
    int d = (i < E) ? ei[E + i] : (i - E);
    atomicAdd(&deg[d], 1);
}

__global__ __launch_bounds__(256) void scan1_kernel(
    const int* __restrict__ deg, int* __restrict__ blockSums, int N)
{
    __shared__ int red[256];
    const int b = blockIdx.x, t = threadIdx.x;
    const int chunk = (N + SCAN_BLOCKS - 1) / SCAN_BLOCKS;
    const int lo = b * chunk;
    const int hi = (lo + chunk < N) ? lo + chunk : N;
    int s = 0;
    for (int i = lo + t; i < hi; i += 256) s += deg[i];
    red[t] = s;
    __syncthreads();
    #pragma unroll
    for (int off = 128; off > 0; off >>= 1) {
        if (t < off) red[t] += red[t + off];
        __syncthreads();
    }
    if (t == 0) blockSums[b] = red[0];
}

// scan2 folded (local re-scan of blockSums) + degree histogram folded.
__global__ __launch_bounds__(256) void scan3b_kernel(
    const int* __restrict__ deg, const int* __restrict__ blockSums,
    int* __restrict__ rowptr, int* __restrict__ cursor,
    int* __restrict__ blockHist, int N)
{
    __shared__ int sh[256];
    __shared__ int lh[256];
    const int b = blockIdx.x, t = threadIdx.x;
    const int chunk = (N + SCAN_BLOCKS - 1) / SCAN_BLOCKS;
    const int lo = b * chunk;
    const int hi = (lo + chunk < N) ? lo + chunk : N;

    lh[t] = 0;
    sh[t] = blockSums[t];
    __syncthreads();
    for (int off = 1; off < 256; off <<= 1) {
        int u = (t >= off) ? sh[t - off] : 0;
        __syncthreads();
        sh[t] += u;
        __syncthreads();
    }
    if (b == 0 && t == 255) rowptr[N] = sh[255];
    int carry = (b == 0) ? 0 : sh[b - 1];
    __syncthreads();

    for (int j = lo; j < hi; j += 256) {
        int i = j + t;
        int v = (i < hi) ? deg[i] : 0;
        sh[t] = v;
        __syncthreads();
        for (int off = 1; off < 256; off <<= 1) {
            int u = (t >= off) ? sh[t - off] : 0;
            __syncthreads();
            sh[t] += u;
            __syncthreads();
        }
        int excl = carry + sh[t] - v;
        if (i < hi) {
            rowptr[i] = excl; cursor[i] = excl;
            atomicAdd(&lh[v > 255 ? 255 : v], 1);    // degree histogram
        }
        carry += sh[255];
        __syncthreads();
    }
    blockHist[b * 256 + t] = lh[t];
}

__global__ void scatter_kernel(const int* __restrict__ ei, int E, int Etot,
                               int* __restrict__ cursor, int* __restrict__ ssrc)
{
    int i = blockIdx.x * blockDim.x + threadIdx.x;
    if (i >= Etot) return;
    int d, s;
    if (i < E) { s = ei[i]; d = ei[E + i]; }
    else       { s = i - E; d = s; }
    int pos = atomicAdd(&cursor[d], 1);
    ssrc[pos] = s;
}

// dscan folded: each block recomputes bin totals + its own offsets.
// chunking matches scan3b (SCAN_BLOCKS).
__global__ __launch_bounds__(256) void dscatter2b_kernel(
    const int* __restrict__ rowptr, const int* __restrict__ blockHist,
    int* __restrict__ dperm, int N)
{
    __shared__ int sh[256];
    __shared__ int cur[256];
    const int b = blockIdx.x, t = threadIdx.x;

    int total = 0, myoff = 0;
    for (int bb = 0; bb < SCAN_BLOCKS; ++bb) {
        int hv = blockHist[bb * 256 + t];
        if (bb < b) myoff += hv;
        total += hv;
    }
    sh[t] = total;
    __syncthreads();
    for (int off = 1; off < 256; off <<= 1) {
        int u = (t >= off) ? sh[t - off] : 0;
        __syncthreads();
        sh[t] += u;
        __syncthreads();
    }
    int grand = sh[255];
    cur[t] = (grand - sh[t]) + myoff;    // descending bin start + block offset
    __syncthreads();

    const int chunk = (N + SCAN_BLOCKS - 1) / SCAN_BLOCKS;
    const int lo = b * chunk;
    const int hi = (lo + chunk < N) ? lo + chunk : N;
    for (int d = lo + t; d < hi; d += 256) {
        int deg = rowptr[d + 1] - rowptr[d];
        int pos = atomicAdd(&cur[deg > 255 ? 255 : deg], 1);
        dperm[pos] = d;
    }
}

// ---------------- fused edge kernel (bf16) with XCD-head affinity ---------
// Assumes blockIdx round-robins XCDs as bid%8 (perf heuristic only).
// H=4: head = (bid&7)>>1 (2 XCDs/head); H=2: head = (bid&7)>>2 (4 XCDs/head).
template <int H, bool OUT_F32, bool OUT_BF16>
__global__ __launch_bounds__(256) void gat_fused4(
    const int* __restrict__ rowptr, const int* __restrict__ ssrc,
    const int* __restrict__ dperm,
    const unsigned short* __restrict__ xl, const unsigned short* __restrict__ xr,
    const float* __restrict__ att, const float* __restrict__ bias,
    float* __restrict__ outf, unsigned short* __restrict__ outb,
    int N, int BPH)
{
    const int bid = blockIdx.x;
    int h, j;
    if (H == 4) {
        h = (bid & 7) >> 1;
        j = ((bid >> 3) << 1) | (bid & 1);
    } else if (H == 2) {
        h = (bid & 7) >> 2;
        j = ((bid >> 3) << 2) | (bid & 3);
    } else {
        h = 0;
        j = bid;
    }
    if (j >= BPH) return;
    const int di = j * 64 + (threadIdx.x >> 2);
    const int sub = threadIdx.x & 3;
    if (di >= N) return;
    const int d  = dperm[di];
    const int HC = H * 64;
    const int so = sub * 16;

    const unsigned short* xlh = xl + (size_t)h * N * 64;

    float xrv[16], attv[16], acc[16];
    {
        const unsigned short* pr = xr + ((size_t)h * N + d) * 64 + so;
        uint4 v0 = *reinterpret_cast<const uint4*>(pr);
        uint4 v1 = *reinterpret_cast<const uint4*>(pr + 8);
        unpack8(v0, xrv); unpack8(v1, xrv + 8);
        const float* pa = att + h * 64 + so;
        #pragma unroll
        for (int k = 0; k < 16; k += 4) {
            float4 w = *reinterpret_cast<const float4*>(pa + k);
            attv[k] = w.x; attv[k+1] = w.y; attv[k+2] = w.z; attv[k+3] = w.w;
        }
    }
    #pragma unroll
    for (int k = 0; k < 16; ++k) acc[k] = 0.f;
    float M = -3.0e38f, S = 0.f;

    const int begin = rowptr[d], end = rowptr[d + 1];
    uint4 c0, c1;
    {
        const unsigned short* pl = xlh + (size_t)ssrc[begin] * 64 + so;
        c0 = *reinterpret_cast<const uint4*>(pl);
        c1 = *reinterpret_cast<const uint4*>(pl + 8);
    }
    for (int e = begin; e < end; ++e) {
        uint4 n0, n1;
        const bool more = (e + 1 < end);
        if (more) {
            const unsigned short* pl = xlh + (size_t)ssrc[e + 1] * 64 + so;
            n0 = *reinterpret_cast<const uint4*>(pl);
            n1 = *reinterpret_cast<const uint4*>(pl + 8);
        }
        float cur[16];
        unpack8(c0, cur);
        unpack8(c1, cur + 8);
        float p = 0.f;
        #pragma unroll
        for (int k = 0; k < 16; ++k) {
            float v = cur[k] + xrv[k];
            v = fmaxf(v, 0.2f * v);           // leaky_relu 0.2
            p = fmaf(v, attv[k], p);
        }
        p += __shfl_xor(p, 1);
        p += __shfl_xor(p, 2);
        float nM = fmaxf(M, p);
        float scale = __expf(M - nM);
        float w = __expf(p - nM);
        S = fmaf(S, scale, w);
        #pragma unroll
        for (int k = 0; k < 16; ++k) acc[k] = fmaf(acc[k], scale, w * cur[k]);
        M = nM;
        if (more) { c0 = n0; c1 = n1; }
    }
    float inv = 1.f / S;
    const float* pb = bias + h * 64 + so;
    #pragma unroll
    for (int k = 0; k < 16; ++k) {
        float val = fmaf(acc[k], inv, pb[k]);
        acc[k] = val > 0.f ? val : 0.f;
    }
    size_t ob = (size_t)d * HC + h * 64 + so;    // node-major output (GEMM A)
    if (OUT_F32) {
        #pragma unroll
        for (int k = 0; k < 16; k += 4) {
            float4 v = {acc[k], acc[k+1], acc[k+2], acc[k+3]};
            *reinterpret_cast<float4*>(outf + ob + k) = v;
        }
    }
    if (OUT_BF16) {
        unsigned pk[8];
        #pragma unroll
        for (int k = 0; k < 8; ++k)
            pk[k] = (unsigned)f2bf(acc[2*k]) | ((unsigned)f2bf(acc[2*k+1]) << 16);
        uint4 lo = {pk[0], pk[1], pk[2], pk[3]};
        uint4 hi = {pk[4], pk[5], pk[6], pk[7]};
        *reinterpret_cast<uint4*>(outb + ob) = lo;
        *reinterpret_cast<uint4*>(outb + ob + 8) = hi;
    }
}

// ---------------- per-graph pool + MLP (no atomics) ------------------------
__global__ __launch_bounds__(1024) void graph_pool_mlp(
    const float* __restrict__ h3, const int* __restrict__ bound,
    const float* __restrict__ Wm1, const float* __restrict__ bm1,
    const float* __restrict__ Wm2, const float* __restrict__ bm2,
    float* __restrict__ out)
{
    __shared__ float sh[1024];
    __shared__ float pooled[64];
    __shared__ float hidden[32];
    const int g = blockIdx.x;
    const int t = threadIdx.x;
    const int ch = t & 63;
    const int slot = t >> 6;              // 0..15
    const int lo = bound[g];
    const int hi = bound[g + 1];

    float acc = 0.f;
    #pragma unroll 4
    for (int n = lo + slot; n < hi; n += 16)
        acc += h3[(size_t)n * 64 + ch];
    sh[t] = acc;
    __syncthreads();
    #pragma unroll
    for (int off = 512; off >= 64; off >>= 1) {
        if (t < off) sh[t] += sh[t + off];
        __syncthreads();
    }
    if (t < 64) {
        float cnt = (float)(hi - lo);
        cnt = cnt > 1.f ? cnt : 1.f;
        pooled[t] = sh[t] / cnt;
    }
    __syncthreads();
    if (t < 32) {
        float a = bm1[t];
        #pragma unroll
        for (int k = 0; k < 64; ++k) a = fmaf(pooled[k], Wm1[k * 32 + t], a);
        hidden[t] = a > 0.f ? a : 0.f;
    }
    __syncthreads();
    if (t < 2) {
        float a = bm2[t];
        #pragma unroll
        for (int j = 0; j < 32; ++j) a = fmaf(hidden[j], Wm2[j * 2 + t], a);
        out[g * 2 + t] = a;
    }
}

// ---------------- layer driver ---------------------------------------------
static void run_layer(const unsigned short* Xb, int K, int H,
                      const float* bl, const float* br,
                      const float* att, const float* bias_out,
                      const unsigned short* Wtl, const unsigned short* Wtr,
                      const int* rowptr, const int* ssrc, const int* dperm, int N,
                      unsigned short* xl, unsigned short* xr,
                      float* houtf, unsigned short* houtb,
                      hipStream_t stream)
{
    int gblocks = (N + 63) / 64;
    if (K == 128 && H == 4)
        gemm_slab<128, 4><<<gblocks, 256, 0, stream>>>(Xb, Wtl, Wtr, bl, br, xl, xr, N);
    else if (K == 256)
        gemm_slab<256, 2><<<gblocks, 256, 0, stream>>>(Xb, Wtl, Wtr, bl, br, xl, xr, N);
    else
        gemm_slab<128, 1><<<gblocks, 256, 0, stream>>>(Xb, Wtl, Wtr, bl, br, xl, xr, N);

    int BPH = (N + 63) / 64;
    if (H == 4) {
        int grid = ((BPH * 4 + 7) / 8) * 8;
        gat_fused4<4, false, true><<<grid, 256, 0, stream>>>(
            rowptr, ssrc, dperm, xl, xr, att, bias_out, houtf, houtb, N, BPH);
    } else if (H == 2) {
        int grid = ((BPH * 2 + 7) / 8) * 8;
        gat_fused4<2, false, true><<<grid, 256, 0, stream>>>(
            rowptr, ssrc, dperm, xl, xr, att, bias_out, houtf, houtb, N, BPH);
    } else {
        gat_fused4<1, true, false><<<BPH, 256, 0, stream>>>(
            rowptr, ssrc, dperm, xl, xr, att, bias_out, houtf, houtb, N, BPH);
    }
}

extern "C" void kernel_launch(void* const* d_in, const int* in_sizes, int n_in,
                              void* d_out, int out_size, void* d_ws, size_t ws_size,
                              hipStream_t stream)
{
    const float* x    = (const float*)d_in[0];
    const int*   ei   = (const int*)d_in[1];
    const int*   batch= (const int*)d_in[2];
    const float* Wl1 = (const float*)d_in[3];
    const float* bl1 = (const float*)d_in[4];
    const float* Wr1 = (const float*)d_in[5];
    const float* br1 = (const float*)d_in[6];
    const float* att1= (const float*)d_in[7];
    const float* b1  = (const float*)d_in[8];
    const float* Wl2 = (const float*)d_in[9];
    const float* bl2 = (const float*)d_in[10];
    const float* Wr2 = (const float*)d_in[11];
    const float* br2 = (const float*)d_in[12];
    const float* att2= (const float*)d_in[13];
    const float* b2  = (const float*)d_in[14];
    const float* Wl3 = (const float*)d_in[15];
    const float* bl3 = (const float*)d_in[16];
    const float* Wr3 = (const float*)d_in[17];
    const float* br3 = (const float*)d_in[18];
    const float* att3= (const float*)d_in[19];
    const float* b3  = (const float*)d_in[20];
    const float* Wm1 = (const float*)d_in[21];
    const float* bm1 = (const float*)d_in[22];
    const float* Wm2 = (const float*)d_in[23];
    const float* bm2 = (const float*)d_in[24];

    const int N    = in_sizes[2];          // 50000
    const int E    = in_sizes[1] / 2;      // 800000
    const int Etot = E + N;                // + self loops
    const int K1   = in_sizes[0] / N;      // 128

    // workspace layout
    char* wsb = (char*)d_ws;
    size_t o = 0;
    auto alloc = [&](size_t bytes) { char* p = wsb + o; o += (bytes + 255) & ~(size_t)255; return p; };
    unsigned short* xl    = (unsigned short*)alloc((size_t)N * 256 * 2);
    unsigned short* xr    = (unsigned short*)alloc((size_t)N * 256 * 2);
    unsigned short* xb    = (unsigned short*)alloc((size_t)N * K1 * 2);
    unsigned short* h1b   = (unsigned short*)alloc((size_t)N * 256 * 2);
    unsigned short* h2b   = (unsigned short*)alloc((size_t)N * 128 * 2);
    float*          h3f   = (float*)alloc((size_t)N * 64 * 4);
    int*   deg    = (int*)alloc((size_t)N * 4);
    int*   rowptr = (int*)alloc((size_t)(N + 1) * 4);
    int*   cursor = (int*)alloc((size_t)N * 4);
    int*   ssrc   = (int*)alloc((size_t)Etot * 4);
    int*   dperm  = (int*)alloc((size_t)N * 4);
    int*   bound  = (int*)alloc(65 * 4);
    int*   blockHist = (int*)alloc((size_t)SCAN_BLOCKS * 256 * 4);
    int*   blockSums = (int*)alloc((size_t)SCAN_BLOCKS * 4);
    unsigned short* Wt1l = (unsigned short*)alloc(128 * 256 * 2);
    unsigned short* Wt1r = (unsigned short*)alloc(128 * 256 * 2);
    unsigned short* Wt2l = (unsigned short*)alloc(256 * 128 * 2);
    unsigned short* Wt2r = (unsigned short*)alloc(256 * 128 * 2);
    unsigned short* Wt3l = (unsigned short*)alloc(128 * 64 * 2);
    unsigned short* Wt3r = (unsigned short*)alloc(128 * 64 * 2);
    (void)ws_size; (void)n_in; (void)out_size;

    // ---- prep: zeros + conversions + graph bounds (1 dispatch) ----
    prep_kernel<<<1024, 256, 0, stream>>>(
        x, batch, N, K1, xb,
        Wl1, Wr1, Wt1l, Wt1r, Wl2, Wr2, Wt2l, Wt2r, Wl3, Wr3, Wt3l, Wt3r,
        deg, bound);

    // ---- CSR build + degree sort (5 dispatches) ----
    hist_kernel<<<(Etot + 255) / 256, 256, 0, stream>>>(ei, E, Etot, deg);
    scan1_kernel<<<SCAN_BLOCKS, 256, 0, stream>>>(deg, blockSums, N);
    scan3b_kernel<<<SCAN_BLOCKS, 256, 0, stream>>>(deg, blockSums, rowptr, cursor, blockHist, N);
    scatter_kernel<<<(Etot + 255) / 256, 256, 0, stream>>>(ei, E, Etot, cursor, ssrc);
    dscatter2b_kernel<<<SCAN_BLOCKS, 256, 0, stream>>>(rowptr, blockHist, dperm, N);

    // ---- layers (6 dispatches) ----
    run_layer(xb, K1, 4, bl1, br1, att1, b1, Wt1l, Wt1r,
              rowptr, ssrc, dperm, N, xl, xr, nullptr, h1b, stream);
    run_layer(h1b, 256, 2, bl2, br2, att2, b2, Wt2l, Wt2r,
              rowptr, ssrc, dperm, N, xl, xr, nullptr, h2b, stream);
    run_layer(h2b, 128, 1, bl3, br3, att3, b3, Wt3l, Wt3r,
              rowptr, ssrc, dperm, N, xl, xr, h3f, nullptr, stream);

    // ---- per-graph pool + MLP (1 dispatch) ----
    graph_pool_mlp<<<64, 1024, 0, stream>>>(
        h3f, bound, Wm1, bm1, Wm2, bm2, (float*)d_out);
}

// Round 16
// 316.355 us; speedup vs baseline: 1.1592x; 1.1592x over previous
//
#include <hip/hip_runtime.h>

// GATv2 GNN classifier.
// R16: unbundled R15. Keep ONLY the proven win (XCD-head affinity edge
// kernel: gat<4> 70->64us, FETCH 191->156MB); revert gemm W-prefetch and
// scan/dhist folds, which together cost ~55us (R15 total regressed 322->367).
// Base = R14 (best: 322us).

typedef __attribute__((ext_vector_type(8))) short bf16x8;
typedef __attribute__((ext_vector_type(4))) float f32x4;

#define SORT_BLOCKS 64
#define SCAN_BLOCKS 256

__device__ inline unsigned short f2bf(float f) {
    unsigned u = __float_as_uint(f);
    unsigned r = (u + 0x7fff + ((u >> 16) & 1)) >> 16;   // RNE
    return (unsigned short)r;
}

__device__ inline void unpack8(uint4 a, float* d) {
    d[0] = __uint_as_float(a.x << 16); d[1] = __uint_as_float(a.x & 0xffff0000u);
    d[2] = __uint_as_float(a.y << 16); d[3] = __uint_as_float(a.y & 0xffff0000u);
    d[4] = __uint_as_float(a.z << 16); d[5] = __uint_as_float(a.z & 0xffff0000u);
    d[6] = __uint_as_float(a.w << 16); d[7] = __uint_as_float(a.w & 0xffff0000u);
}

// ---------------- prep: zeros + x->bf16 + W transposes + graph bounds -----
__global__ __launch_bounds__(256) void prep_kernel(
    const float* __restrict__ x, const int* __restrict__ batch, int N, int K1,
    unsigned short* __restrict__ xb,
    const float* __restrict__ Wl1, const float* __restrict__ Wr1,
    unsigned short* __restrict__ T1l, unsigned short* __restrict__ T1r,
    const float* __restrict__ Wl2, const float* __restrict__ Wr2,
    unsigned short* __restrict__ T2l, unsigned short* __restrict__ T2r,
    const float* __restrict__ Wl3, const float* __restrict__ Wr3,
    unsigned short* __restrict__ T3l, unsigned short* __restrict__ T3r,
    int* __restrict__ deg, int* __restrict__ bound)
{
    const int gtid = blockIdx.x * 256 + threadIdx.x;
    const int gsz = (int)gridDim.x * 256;

    for (int i = gtid; i < N; i += gsz) deg[i] = 0;

    // graph boundaries: bound[g] = first node n with batch[n] >= g
    for (int n = gtid; n < N; n += gsz) {
        int bn = batch[n];
        int prev = (n == 0) ? -1 : batch[n - 1];
        for (int g = prev + 1; g <= bn; ++g) bound[g] = n;
        if (n == N - 1)
            for (int g = bn + 1; g <= 64; ++g) bound[g] = N;
    }

    {
        int n4 = (N * K1) >> 2;
        for (int i = gtid; i < n4; i += gsz) {
            float4 v = *reinterpret_cast<const float4*>(x + (size_t)i * 4);
            ushort4 o;
            o.x = f2bf(v.x); o.y = f2bf(v.y); o.z = f2bf(v.z); o.w = f2bf(v.w);
            *reinterpret_cast<ushort4*>(xb + (size_t)i * 4) = o;
        }
    }
    for (int id = gtid; id < 147456; id += gsz) {
        const float* W; unsigned short* T; int K, No, idx;
        if (id < 65536) {                    // layer1: 128x256
            K = 128; No = 256; idx = id & 32767;
            W = (id < 32768) ? Wl1 : Wr1; T = (id < 32768) ? T1l : T1r;
        } else if (id < 131072) {            // layer2: 256x128
            int v = id - 65536; K = 256; No = 128; idx = v & 32767;
            W = (v < 32768) ? Wl2 : Wr2; T = (v < 32768) ? T2l : T2r;
        } else {                             // layer3: 128x64
            int v = id - 131072; K = 128; No = 64; idx = v & 8191;
            W = (v < 8192) ? Wl3 : Wr3; T = (v < 8192) ? T3l : T3r;
        }
        int n = idx / K, k = idx - n * K;
        T[idx] = f2bf(W[(size_t)k * No + n]);
    }
}

// ---------------- A-resident slab GEMM (bf16 MFMA, R14) --------------------
template <int K, int NY>
__global__ __launch_bounds__(256) void gemm_slab(
    const unsigned short* __restrict__ A,     // [M][K] bf16
    const unsigned short* __restrict__ W0, const unsigned short* __restrict__ W1,
    const float* __restrict__ bias0, const float* __restrict__ bias1,
    unsigned short* __restrict__ OutL, unsigned short* __restrict__ OutR,
    int M)
{
    constexpr int CPR = K / 8;                 // 16B chunks per A row
    __shared__ __align__(16) char As[64 * K * 2];
    __shared__ __align__(16) char Bs[64 * 128 * 2];   // W k-half stage / C stage

    const int t = threadIdx.x;
    const int lane = t & 63;
    const int wid = t >> 6;
    const int row0 = blockIdx.x * 64;

    #pragma unroll
    for (int i = 0; i < (64 * CPR) / 256; ++i) {
        int c16 = i * 256 + t;
        int r = c16 / CPR, j = c16 % CPR;
        int gr = row0 + r; if (gr > M - 1) gr = M - 1;
        uint4 v = *reinterpret_cast<const uint4*>(A + (size_t)gr * K + j * 8);
        *reinterpret_cast<uint4*>(As + r * (2 * K) + ((j ^ (r & 7)) << 4)) = v;
    }

    const int ra = wid * 16 + (lane & 15);
    const int rowA_byte = ra * (2 * K);

    for (int z = 0; z < 2; ++z) {
        const unsigned short* Wt = z ? W1 : W0;   // [NY*64][K]
        const float* bias = z ? bias1 : bias0;
        unsigned short* Out = z ? OutR : OutL;
        for (int y = 0; y < NY; ++y) {
            f32x4 acc[4];
            #pragma unroll
            for (int j = 0; j < 4; ++j) acc[j] = (f32x4){0.f, 0.f, 0.f, 0.f};

            #pragma unroll
            for (int kh = 0; kh < K / 128; ++kh) {
                __syncthreads();
                #pragma unroll
                for (int i = 0; i < 4; ++i) {   // stage W tile 64x128 bf16
                    int c16 = i * 256 + t;
                    int n = c16 >> 4, j = c16 & 15;
                    uint4 v = *reinterpret_cast<const uint4*>(
                        Wt + (size_t)(y * 64 + n) * K + kh * 128 + j * 8);
                    *reinterpret_cast<uint4*>(Bs + n * 256 + ((j ^ (n & 7)) << 4)) = v;
                }
                __syncthreads();
                #pragma unroll
                for (int ks = 0; ks < 4; ++ks) {
                    int chA = kh * 16 + ks * 4 + (lane >> 4);
                    bf16x8 a = *reinterpret_cast<const bf16x8*>(
                        As + rowA_byte + ((chA ^ (ra & 7)) << 4));
                    #pragma unroll
                    for (int j = 0; j < 4; ++j) {
                        int nb = j * 16 + (lane & 15);
                        int chB = ks * 4 + (lane >> 4);
                        bf16x8 b = *reinterpret_cast<const bf16x8*>(
                            Bs + nb * 256 + ((chB ^ (nb & 7)) << 4));
                        acc[j] = __builtin_amdgcn_mfma_f32_16x16x32_bf16(a, b, acc[j], 0, 0, 0);
                    }
                }
            }
            __syncthreads();            // all Bs reads done
            #pragma unroll
            for (int j = 0; j < 4; ++j) {
                float bb = bias[y * 64 + j * 16 + (lane & 15)];
                #pragma unroll
                for (int q = 0; q < 4; ++q) {
                    int r = wid * 16 + (lane >> 4) * 4 + q;
                    int c = j * 16 + (lane & 15);
                    *reinterpret_cast<unsigned short*>(Bs + r * 128 + c * 2)
                        = f2bf(acc[j][q] + bb);
                }
            }
            __syncthreads();
            {
                int r = t >> 2, ch = t & 3;
                int gr = row0 + r;
                if (gr < M) {
                    const uint4* src = reinterpret_cast<const uint4*>(Bs + r * 128 + ch * 32);
                    uint4 v0 = src[0], v1 = src[1];
                    uint4* dst = reinterpret_cast<uint4*>(
                        Out + ((size_t)y * M + gr) * 64 + ch * 16);
                    dst[0] = v0; dst[1] = v1;
                }
            }
        }
    }
}

// ---------------- CSR build ------------------------------------------------
__global__ void hist_kernel(const int* __restrict__ ei, int E, int Etot,
                            int* __restrict__ deg)
{
    int i = blockIdx.x * blockDim.x + threadIdx.x;
    if (i >= Etot) return;
    int d = (i < E) ? ei[E + i] : (i - E);
    atomicAdd(&deg[d], 1);
}

__global__ __launch_bounds__(256) void scan1_kernel(
    const int* __restrict__ deg, int* __restrict__ blockSums, int N)
{
    __shared__ int red[256];
    const int b = blockIdx.x, t = threadIdx.x;
    const int chunk = (N + SCAN_BLOCKS - 1) / SCAN_BLOCKS;
    const int lo = b * chunk;
    const int hi = (lo + chunk < N) ? lo + chunk : N;
    int s = 0;
    for (int i = lo + t; i < hi; i += 256) s += deg[i];
    red[t] = s;
    __syncthreads();
    #pragma unroll
    for (int off = 128; off > 0; off >>= 1) {
        if (t < off) red[t] += red[t + off];
        __syncthreads();
    }
    if (t == 0) blockSums[b] = red[0];
}

// scan2 folded in: each block re-scans blockSums locally, then local scan.
__global__ __launch_bounds__(256) void scan3b_kernel(
    const int* __restrict__ deg, const int* __restrict__ blockSums,
    int* __restrict__ rowptr, int* __restrict__ cursor, int N)
{
    __shared__ int sh[256];
    const int b = blockIdx.x, t = threadIdx.x;
    const int chunk = (N + SCAN_BLOCKS - 1) / SCAN_BLOCKS;
    const int lo = b * chunk;
    const int hi = (lo + chunk < N) ? lo + chunk : N;

    sh[t] = blockSums[t];
    __syncthreads();
    for (int off = 1; off < 256; off <<= 1) {
        int u = (t >= off) ? sh[t - off] : 0;
        __syncthreads();
        sh[t] += u;
        __syncthreads();
    }
    if (b == 0 && t == 255) rowptr[N] = sh[255];
    int carry = (b == 0) ? 0 : sh[b - 1];
    __syncthreads();

    for (int j = lo; j < hi; j += 256) {
        int i = j + t;
        int v = (i < hi) ? deg[i] : 0;
        sh[t] = v;
        __syncthreads();
        for (int off = 1; off < 256; off <<= 1) {
            int u = (t >= off) ? sh[t - off] : 0;
            __syncthreads();
            sh[t] += u;
            __syncthreads();
        }
        int excl = carry + sh[t] - v;
        if (i < hi) { rowptr[i] = excl; cursor[i] = excl; }
        carry += sh[255];
        __syncthreads();
    }
}

__global__ void scatter_kernel(const int* __restrict__ ei, int E, int Etot,
                               int* __restrict__ cursor, int* __restrict__ ssrc)
{
    int i = blockIdx.x * blockDim.x + threadIdx.x;
    if (i >= Etot) return;
    int d, s;
    if (i < E) { s = ei[i]; d = ei[E + i]; }
    else       { s = i - E; d = s; }
    int pos = atomicAdd(&cursor[d], 1);
    ssrc[pos] = s;
}

// ---------------- degree sort (DESCENDING), contention-free ---------------
__global__ __launch_bounds__(256) void dhist2_kernel(
    const int* __restrict__ rowptr, int* __restrict__ blockHist, int N)
{
    __shared__ int lh[256];
    lh[threadIdx.x] = 0;
    __syncthreads();
    const int chunk = (N + SORT_BLOCKS - 1) / SORT_BLOCKS;
    const int lo = blockIdx.x * chunk;
    const int hi = (lo + chunk < N) ? lo + chunk : N;
    for (int d = lo + threadIdx.x; d < hi; d += 256) {
        int deg = rowptr[d + 1] - rowptr[d];
        atomicAdd(&lh[deg > 255 ? 255 : deg], 1);
    }
    __syncthreads();
    blockHist[blockIdx.x * 256 + threadIdx.x] = lh[threadIdx.x];
}

// dscan2 folded in: each block recomputes bin totals + its own offsets.
__global__ __launch_bounds__(256) void dscatter2b_kernel(
    const int* __restrict__ rowptr, const int* __restrict__ blockHist,
    int* __restrict__ dperm, int N)
{
    __shared__ int sh[256];
    __shared__ int cur[256];
    const int b = blockIdx.x, t = threadIdx.x;

    int total = 0, myoff = 0;
    for (int bb = 0; bb < SORT_BLOCKS; ++bb) {
        int hv = blockHist[bb * 256 + t];
        if (bb < b) myoff += hv;
        total += hv;
    }
    sh[t] = total;
    __syncthreads();
    for (int off = 1; off < 256; off <<= 1) {
        int u = (t >= off) ? sh[t - off] : 0;
        __syncthreads();
        sh[t] += u;
        __syncthreads();
    }
    int grand = sh[255];
    cur[t] = (grand - sh[t]) + myoff;    // descending bin start + block offset
    __syncthreads();

    const int chunk = (N + SORT_BLOCKS - 1) / SORT_BLOCKS;
    const int lo = b * chunk;
    const int hi = (lo + chunk < N) ? lo + chunk : N;
    for (int d = lo + t; d < hi; d += 256) {
        int deg = rowptr[d + 1] - rowptr[d];
        int pos = atomicAdd(&cur[deg > 255 ? 255 : deg], 1);
        dperm[pos] = d;
    }
}

// ---------------- fused edge kernel (bf16) with XCD-head affinity ---------
// Assumes blockIdx round-robins XCDs as bid%8 (perf heuristic only).
// H=4: head = (bid&7)>>1 (2 XCDs/head); H=2: head = (bid&7)>>2 (4 XCDs/head).
template <int H, bool OUT_F32, bool OUT_BF16>
__global__ __launch_bounds__(256) void gat_fused4(
    const int* __restrict__ rowptr, const int* __restrict__ ssrc,
    const int* __restrict__ dperm,
    const unsigned short* __restrict__ xl, const unsigned short* __restrict__ xr,
    const float* __restrict__ att, const float* __restrict__ bias,
    float* __restrict__ outf, unsigned short* __restrict__ outb,
    int N, int BPH)
{
    const int bid = blockIdx.x;
    int h, j;
    if (H == 4) {
        h = (bid & 7) >> 1;
        j = ((bid >> 3) << 1) | (bid & 1);
    } else if (H == 2) {
        h = (bid & 7) >> 2;
        j = ((bid >> 3) << 2) | (bid & 3);
    } else {
        h = 0;
        j = bid;
    }
    if (j >= BPH) return;
    const int di = j * 64 + (threadIdx.x >> 2);
    const int sub = threadIdx.x & 3;
    if (di >= N) return;
    const int d  = dperm[di];
    const int HC = H * 64;
    const int so = sub * 16;

    const unsigned short* xlh = xl + (size_t)h * N * 64;

    float xrv[16], attv[16], acc[16];
    {
        const unsigned short* pr = xr + ((size_t)h * N + d) * 64 + so;
        uint4 v0 = *reinterpret_cast<const uint4*>(pr);
        uint4 v1 = *reinterpret_cast<const uint4*>(pr + 8);
        unpack8(v0, xrv); unpack8(v1, xrv + 8);
        const float* pa = att + h * 64 + so;
        #pragma unroll
        for (int k = 0; k < 16; k += 4) {
            float4 w = *reinterpret_cast<const float4*>(pa + k);
            attv[k] = w.x; attv[k+1] = w.y; attv[k+2] = w.z; attv[k+3] = w.w;
        }
    }
    #pragma unroll
    for (int k = 0; k < 16; ++k) acc[k] = 0.f;
    float M = -3.0e38f, S = 0.f;

    const int begin = rowptr[d], end = rowptr[d + 1];
    uint4 c0, c1;
    {
        const unsigned short* pl = xlh + (size_t)ssrc[begin] * 64 + so;
        c0 = *reinterpret_cast<const uint4*>(pl);
        c1 = *reinterpret_cast<const uint4*>(pl + 8);
    }
    for (int e = begin; e < end; ++e) {
        uint4 n0, n1;
        const bool more = (e + 1 < end);
        if (more) {
            const unsigned short* pl = xlh + (size_t)ssrc[e + 1] * 64 + so;
            n0 = *reinterpret_cast<const uint4*>(pl);
            n1 = *reinterpret_cast<const uint4*>(pl + 8);
        }
        float cur[16];
        unpack8(c0, cur);
        unpack8(c1, cur + 8);
        float p = 0.f;
        #pragma unroll
        for (int k = 0; k < 16; ++k) {
            float v = cur[k] + xrv[k];
            v = fmaxf(v, 0.2f * v);           // leaky_relu 0.2
            p = fmaf(v, attv[k], p);
        }
        p += __shfl_xor(p, 1);
        p += __shfl_xor(p, 2);
        float nM = fmaxf(M, p);
        float scale = __expf(M - nM);
        float w = __expf(p - nM);
        S = fmaf(S, scale, w);
        #pragma unroll
        for (int k = 0; k < 16; ++k) acc[k] = fmaf(acc[k], scale, w * cur[k]);
        M = nM;
        if (more) { c0 = n0; c1 = n1; }
    }
    float inv = 1.f / S;
    const float* pb = bias + h * 64 + so;
    #pragma unroll
    for (int k = 0; k < 16; ++k) {
        float val = fmaf(acc[k], inv, pb[k]);
        acc[k] = val > 0.f ? val : 0.f;
    }
    size_t ob = (size_t)d * HC + h * 64 + so;    // node-major output (GEMM A)
    if (OUT_F32) {
        #pragma unroll
        for (int k = 0; k < 16; k += 4) {
            float4 v = {acc[k], acc[k+1], acc[k+2], acc[k+3]};
            *reinterpret_cast<float4*>(outf + ob + k) = v;
        }
    }
    if (OUT_BF16) {
        unsigned pk[8];
        #pragma unroll
        for (int k = 0; k < 8; ++k)
            pk[k] = (unsigned)f2bf(acc[2*k]) | ((unsigned)f2bf(acc[2*k+1]) << 16);
        uint4 lo = {pk[0], pk[1], pk[2], pk[3]};
        uint4 hi = {pk[4], pk[5], pk[6], pk[7]};
        *reinterpret_cast<uint4*>(outb + ob) = lo;
        *reinterpret_cast<uint4*>(outb + ob + 8) = hi;
    }
}

// ---------------- per-graph pool + MLP (no atomics) ------------------------
__global__ __launch_bounds__(1024) void graph_pool_mlp(
    const float* __restrict__ h3, const int* __restrict__ bound,
    const float* __restrict__ Wm1, const float* __restrict__ bm1,
    const float* __restrict__ Wm2, const float* __restrict__ bm2,
    float* __restrict__ out)
{
    __shared__ float sh[1024];
    __shared__ float pooled[64];
    __shared__ float hidden[32];
    const int g = blockIdx.x;
    const int t = threadIdx.x;
    const int ch = t & 63;
    const int slot = t >> 6;              // 0..15
    const int lo = bound[g];
    const int hi = bound[g + 1];

    float acc = 0.f;
    #pragma unroll 4
    for (int n = lo + slot; n < hi; n += 16)
        acc += h3[(size_t)n * 64 + ch];
    sh[t] = acc;
    __syncthreads();
    #pragma unroll
    for (int off = 512; off >= 64; off >>= 1) {
        if (t < off) sh[t] += sh[t + off];
        __syncthreads();
    }
    if (t < 64) {
        float cnt = (float)(hi - lo);
        cnt = cnt > 1.f ? cnt : 1.f;
        pooled[t] = sh[t] / cnt;
    }
    __syncthreads();
    if (t < 32) {
        float a = bm1[t];
        #pragma unroll
        for (int k = 0; k < 64; ++k) a = fmaf(pooled[k], Wm1[k * 32 + t], a);
        hidden[t] = a > 0.f ? a : 0.f;
    }
    __syncthreads();
    if (t < 2) {
        float a = bm2[t];
        #pragma unroll
        for (int j = 0; j < 32; ++j) a = fmaf(hidden[j], Wm2[j * 2 + t], a);
        out[g * 2 + t] = a;
    }
}

// ---------------- layer driver ---------------------------------------------
static void run_layer(const unsigned short* Xb, int K, int H,
                      const float* bl, const float* br,
                      const float* att, const float* bias_out,
                      const unsigned short* Wtl, const unsigned short* Wtr,
                      const int* rowptr, const int* ssrc, const int* dperm, int N,
                      unsigned short* xl, unsigned short* xr,
                      float* houtf, unsigned short* houtb,
                      hipStream_t stream)
{
    int gblocks = (N + 63) / 64;
    if (K == 128 && H == 4)
        gemm_slab<128, 4><<<gblocks, 256, 0, stream>>>(Xb, Wtl, Wtr, bl, br, xl, xr, N);
    else if (K == 256)
        gemm_slab<256, 2><<<gblocks, 256, 0, stream>>>(Xb, Wtl, Wtr, bl, br, xl, xr, N);
    else
        gemm_slab<128, 1><<<gblocks, 256, 0, stream>>>(Xb, Wtl, Wtr, bl, br, xl, xr, N);

    int BPH = (N + 63) / 64;
    if (H == 4) {
        int grid = ((BPH * 4 + 7) / 8) * 8;
        gat_fused4<4, false, true><<<grid, 256, 0, stream>>>(
            rowptr, ssrc, dperm, xl, xr, att, bias_out, houtf, houtb, N, BPH);
    } else if (H == 2) {
        int grid = ((BPH * 2 + 7) / 8) * 8;
        gat_fused4<2, false, true><<<grid, 256, 0, stream>>>(
            rowptr, ssrc, dperm, xl, xr, att, bias_out, houtf, houtb, N, BPH);
    } else {
        gat_fused4<1, true, false><<<BPH, 256, 0, stream>>>(
            rowptr, ssrc, dperm, xl, xr, att, bias_out, houtf, houtb, N, BPH);
    }
}

extern "C" void kernel_launch(void* const* d_in, const int* in_sizes, int n_in,
                              void* d_out, int out_size, void* d_ws, size_t ws_size,
                              hipStream_t stream)
{
    const float* x    = (const float*)d_in[0];
    const int*   ei   = (const int*)d_in[1];
    const int*   batch= (const int*)d_in[2];
    const float* Wl1 = (const float*)d_in[3];
    const float* bl1 = (const float*)d_in[4];
    const float* Wr1 = (const float*)d_in[5];
    const float* br1 = (const float*)d_in[6];
    const float* att1= (const float*)d_in[7];
    const float* b1  = (const float*)d_in[8];
    const float* Wl2 = (const float*)d_in[9];
    const float* bl2 = (const float*)d_in[10];
    const float* Wr2 = (const float*)d_in[11];
    const float* br2 = (const float*)d_in[12];
    const float* att2= (const float*)d_in[13];
    const float* b2  = (const float*)d_in[14];
    const float* Wl3 = (const float*)d_in[15];
    const float* bl3 = (const float*)d_in[16];
    const float* Wr3 = (const float*)d_in[17];
    const float* br3 = (const float*)d_in[18];
    const float* att3= (const float*)d_in[19];
    const float* b3  = (const float*)d_in[20];
    const float* Wm1 = (const float*)d_in[21];
    const float* bm1 = (const float*)d_in[22];
    const float* Wm2 = (const float*)d_in[23];
    const float* bm2 = (const float*)d_in[24];

    const int N    = in_sizes[2];          // 50000
    const int E    = in_sizes[1] / 2;      // 800000
    const int Etot = E + N;                // + self loops
    const int K1   = in_sizes[0] / N;      // 128

    // workspace layout
    char* wsb = (char*)d_ws;
    size_t o = 0;
    auto alloc = [&](size_t bytes) { char* p = wsb + o; o += (bytes + 255) & ~(size_t)255; return p; };
    unsigned short* xl    = (unsigned short*)alloc((size_t)N * 256 * 2);
    unsigned short* xr    = (unsigned short*)alloc((size_t)N * 256 * 2);
    unsigned short* xb    = (unsigned short*)alloc((size_t)N * K1 * 2);
    unsigned short* h1b   = (unsigned short*)alloc((size_t)N * 256 * 2);
    unsigned short* h2b   = (unsigned short*)alloc((size_t)N * 128 * 2);
    float*          h3f   = (float*)alloc((size_t)N * 64 * 4);
    int*   deg    = (int*)alloc((size_t)N * 4);
    int*   rowptr = (int*)alloc((size_t)(N + 1) * 4);
    int*   cursor = (int*)alloc((size_t)N * 4);
    int*   ssrc   = (int*)alloc((size_t)Etot * 4);
    int*   dperm  = (int*)alloc((size_t)N * 4);
    int*   bound  = (int*)alloc(65 * 4);
    int*   blockHist = (int*)alloc((size_t)SORT_BLOCKS * 256 * 4);
    int*   blockSums = (int*)alloc((size_t)SCAN_BLOCKS * 4);
    unsigned short* Wt1l = (unsigned short*)alloc(128 * 256 * 2);
    unsigned short* Wt1r = (unsigned short*)alloc(128 * 256 * 2);
    unsigned short* Wt2l = (unsigned short*)alloc(256 * 128 * 2);
    unsigned short* Wt2r = (unsigned short*)alloc(256 * 128 * 2);
    unsigned short* Wt3l = (unsigned short*)alloc(128 * 64 * 2);
    unsigned short* Wt3r = (unsigned short*)alloc(128 * 64 * 2);
    (void)ws_size; (void)n_in; (void)out_size;

    // ---- prep: zeros + conversions + graph bounds (1 dispatch) ----
    prep_kernel<<<1024, 256, 0, stream>>>(
        x, batch, N, K1, xb,
        Wl1, Wr1, Wt1l, Wt1r, Wl2, Wr2, Wt2l, Wt2r, Wl3, Wr3, Wt3l, Wt3r,
        deg, bound);

    // ---- CSR build + degree sort (6 dispatches) ----
    hist_kernel<<<(Etot + 255) / 256, 256, 0, stream>>>(ei, E, Etot, deg);
    scan1_kernel<<<SCAN_BLOCKS, 256, 0, stream>>>(deg, blockSums, N);
    scan3b_kernel<<<SCAN_BLOCKS, 256, 0, stream>>>(deg, blockSums, rowptr, cursor, N);
    scatter_kernel<<<(Etot + 255) / 256, 256, 0, stream>>>(ei, E, Etot, cursor, ssrc);
    dhist2_kernel<<<SORT_BLOCKS, 256, 0, stream>>>(rowptr, blockHist, N);
    dscatter2b_kernel<<<SORT_BLOCKS, 256, 0, stream>>>(rowptr, blockHist, dperm, N);

    // ---- layers (6 dispatches) ----
    run_layer(xb, K1, 4, bl1, br1, att1, b1, Wt1l, Wt1r,
              rowptr, ssrc, dperm, N, xl, xr, nullptr, h1b, stream);
    run_layer(h1b, 256, 2, bl2, br2, att2, b2, Wt2l, Wt2r,
              rowptr, ssrc, dperm, N, xl, xr, nullptr, h2b, stream);
    run_layer(h2b, 128, 1, bl3, br3, att3, b3, Wt3l, Wt3r,
              rowptr, ssrc, dperm, N, xl, xr, h3f, nullptr, stream);

    // ---- per-graph pool + MLP (1 dispatch) ----
    graph_pool_mlp<<<64, 1024, 0, stream>>>(
        h3f, bound, Wm1, bm1, Wm2, bm2, (float*)d_out);
}

// Round 17
// 308.450 us; speedup vs baseline: 1.1889x; 1.0256x over previous
//
#include <hip/hip_runtime.h>

// GATv2 GNN classifier.
// R17: (a) depth-2 gather pipeline in bf16 edge kernel (cover residual
// L2/L3-miss latency; R16 showed VALUBusy 72-74% + 36% HBM mixed-bound);
// (b) scatter+dhist2 merged into one dispatch (independent after scan3b).
// Base = R16 (best: 316us; XCD-head affinity edge + R14 kernel set).

typedef __attribute__((ext_vector_type(8))) short bf16x8;
typedef __attribute__((ext_vector_type(4))) float f32x4;

#define SORT_BLOCKS 64
#define SCAN_BLOCKS 256

__device__ inline unsigned short f2bf(float f) {
    unsigned u = __float_as_uint(f);
    unsigned r = (u + 0x7fff + ((u >> 16) & 1)) >> 16;   // RNE
    return (unsigned short)r;
}

__device__ inline void unpack8(uint4 a, float* d) {
    d[0] = __uint_as_float(a.x << 16); d[1] = __uint_as_float(a.x & 0xffff0000u);
    d[2] = __uint_as_float(a.y << 16); d[3] = __uint_as_float(a.y & 0xffff0000u);
    d[4] = __uint_as_float(a.z << 16); d[5] = __uint_as_float(a.z & 0xffff0000u);
    d[6] = __uint_as_float(a.w << 16); d[7] = __uint_as_float(a.w & 0xffff0000u);
}

// ---------------- prep: zeros + x->bf16 + W transposes + graph bounds -----
__global__ __launch_bounds__(256) void prep_kernel(
    const float* __restrict__ x, const int* __restrict__ batch, int N, int K1,
    unsigned short* __restrict__ xb,
    const float* __restrict__ Wl1, const float* __restrict__ Wr1,
    unsigned short* __restrict__ T1l, unsigned short* __restrict__ T1r,
    const float* __restrict__ Wl2, const float* __restrict__ Wr2,
    unsigned short* __restrict__ T2l, unsigned short* __restrict__ T2r,
    const float* __restrict__ Wl3, const float* __restrict__ Wr3,
    unsigned short* __restrict__ T3l, unsigned short* __restrict__ T3r,
    int* __restrict__ deg, int* __restrict__ bound)
{
    const int gtid = blockIdx.x * 256 + threadIdx.x;
    const int gsz = (int)gridDim.x * 256;

    for (int i = gtid; i < N; i += gsz) deg[i] = 0;

    // graph boundaries: bound[g] = first node n with batch[n] >= g
    for (int n = gtid; n < N; n += gsz) {
        int bn = batch[n];
        int prev = (n == 0) ? -1 : batch[n - 1];
        for (int g = prev + 1; g <= bn; ++g) bound[g] = n;
        if (n == N - 1)
            for (int g = bn + 1; g <= 64; ++g) bound[g] = N;
    }

    {
        int n4 = (N * K1) >> 2;
        for (int i = gtid; i < n4; i += gsz) {
            float4 v = *reinterpret_cast<const float4*>(x + (size_t)i * 4);
            ushort4 o;
            o.x = f2bf(v.x); o.y = f2bf(v.y); o.z = f2bf(v.z); o.w = f2bf(v.w);
            *reinterpret_cast<ushort4*>(xb + (size_t)i * 4) = o;
        }
    }
    for (int id = gtid; id < 147456; id += gsz) {
        const float* W; unsigned short* T; int K, No, idx;
        if (id < 65536) {                    // layer1: 128x256
            K = 128; No = 256; idx = id & 32767;
            W = (id < 32768) ? Wl1 : Wr1; T = (id < 32768) ? T1l : T1r;
        } else if (id < 131072) {            // layer2: 256x128
            int v = id - 65536; K = 256; No = 128; idx = v & 32767;
            W = (v < 32768) ? Wl2 : Wr2; T = (v < 32768) ? T2l : T2r;
        } else {                             // layer3: 128x64
            int v = id - 131072; K = 128; No = 64; idx = v & 8191;
            W = (v < 8192) ? Wl3 : Wr3; T = (v < 8192) ? T3l : T3r;
        }
        int n = idx / K, k = idx - n * K;
        T[idx] = f2bf(W[(size_t)k * No + n]);
    }
}

// ---------------- A-resident slab GEMM (bf16 MFMA, R14) --------------------
template <int K, int NY>
__global__ __launch_bounds__(256) void gemm_slab(
    const unsigned short* __restrict__ A,     // [M][K] bf16
    const unsigned short* __restrict__ W0, const unsigned short* __restrict__ W1,
    const float* __restrict__ bias0, const float* __restrict__ bias1,
    unsigned short* __restrict__ OutL, unsigned short* __restrict__ OutR,
    int M)
{
    constexpr int CPR = K / 8;                 // 16B chunks per A row
    __shared__ __align__(16) char As[64 * K * 2];
    __shared__ __align__(16) char Bs[64 * 128 * 2];   // W k-half stage / C stage

    const int t = threadIdx.x;
    const int lane = t & 63;
    const int wid = t >> 6;
    const int row0 = blockIdx.x * 64;

    #pragma unroll
    for (int i = 0; i < (64 * CPR) / 256; ++i) {
        int c16 = i * 256 + t;
        int r = c16 / CPR, j = c16 % CPR;
        int gr = row0 + r; if (gr > M - 1) gr = M - 1;
        uint4 v = *reinterpret_cast<const uint4*>(A + (size_t)gr * K + j * 8);
        *reinterpret_cast<uint4*>(As + r * (2 * K) + ((j ^ (r & 7)) << 4)) = v;
    }

    const int ra = wid * 16 + (lane & 15);
    const int rowA_byte = ra * (2 * K);

    for (int z = 0; z < 2; ++z) {
        const unsigned short* Wt = z ? W1 : W0;   // [NY*64][K]
        const float* bias = z ? bias1 : bias0;
        unsigned short* Out = z ? OutR : OutL;
        for (int y = 0; y < NY; ++y) {
            f32x4 acc[4];
            #pragma unroll
            for (int j = 0; j < 4; ++j) acc[j] = (f32x4){0.f, 0.f, 0.f, 0.f};

            #pragma unroll
            for (int kh = 0; kh < K / 128; ++kh) {
                __syncthreads();
                #pragma unroll
                for (int i = 0; i < 4; ++i) {   // stage W tile 64x128 bf16
                    int c16 = i * 256 + t;
                    int n = c16 >> 4, j = c16 & 15;
                    uint4 v = *reinterpret_cast<const uint4*>(
                        Wt + (size_t)(y * 64 + n) * K + kh * 128 + j * 8);
                    *reinterpret_cast<uint4*>(Bs + n * 256 + ((j ^ (n & 7)) << 4)) = v;
                }
                __syncthreads();
                #pragma unroll
                for (int ks = 0; ks < 4; ++ks) {
                    int chA = kh * 16 + ks * 4 + (lane >> 4);
                    bf16x8 a = *reinterpret_cast<const bf16x8*>(
                        As + rowA_byte + ((chA ^ (ra & 7)) << 4));
                    #pragma unroll
                    for (int j = 0; j < 4; ++j) {
                        int nb = j * 16 + (lane & 15);
                        int chB = ks * 4 + (lane >> 4);
                        bf16x8 b = *reinterpret_cast<const bf16x8*>(
                            Bs + nb * 256 + ((chB ^ (nb & 7)) << 4));
                        acc[j] = __builtin_amdgcn_mfma_f32_16x16x32_bf16(a, b, acc[j], 0, 0, 0);
                    }
                }
            }
            __syncthreads();            // all Bs reads done
            #pragma unroll
            for (int j = 0; j < 4; ++j) {
                float bb = bias[y * 64 + j * 16 + (lane & 15)];
                #pragma unroll
                for (int q = 0; q < 4; ++q) {
                    int r = wid * 16 + (lane >> 4) * 4 + q;
                    int c = j * 16 + (lane & 15);
                    *reinterpret_cast<unsigned short*>(Bs + r * 128 + c * 2)
                        = f2bf(acc[j][q] + bb);
                }
            }
            __syncthreads();
            {
                int r = t >> 2, ch = t & 3;
                int gr = row0 + r;
                if (gr < M) {
                    const uint4* src = reinterpret_cast<const uint4*>(Bs + r * 128 + ch * 32);
                    uint4 v0 = src[0], v1 = src[1];
                    uint4* dst = reinterpret_cast<uint4*>(
                        Out + ((size_t)y * M + gr) * 64 + ch * 16);
                    dst[0] = v0; dst[1] = v1;
                }
            }
        }
    }
}

// ---------------- CSR build ------------------------------------------------
__global__ void hist_kernel(const int* __restrict__ ei, int E, int Etot,
                            int* __restrict__ deg)
{
    int i = blockIdx.x * blockDim.x + threadIdx.x;
    if (i >= Etot) return;
    int d = (i < E) ? ei[E + i] : (i - E);
    atomicAdd(&deg[d], 1);
}

__global__ __launch_bounds__(256) void scan1_kernel(
    const int* __restrict__ deg, int* __restrict__ blockSums, int N)
{
    __shared__ int red[256];
    const int b = blockIdx.x, t = threadIdx.x;
    const int chunk = (N + SCAN_BLOCKS - 1) / SCAN_BLOCKS;
    const int lo = b * chunk;
    const int hi = (lo + chunk < N) ? lo + chunk : N;
    int s = 0;
    for (int i = lo + t; i < hi; i += 256) s += deg[i];
    red[t] = s;
    __syncthreads();
    #pragma unroll
    for (int off = 128; off > 0; off >>= 1) {
        if (t < off) red[t] += red[t + off];
        __syncthreads();
    }
    if (t == 0) blockSums[b] = red[0];
}

// scan2 folded in: each block re-scans blockSums locally, then local scan.
__global__ __launch_bounds__(256) void scan3b_kernel(
    const int* __restrict__ deg, const int* __restrict__ blockSums,
    int* __restrict__ rowptr, int* __restrict__ cursor, int N)
{
    __shared__ int sh[256];
    const int b = blockIdx.x, t = threadIdx.x;
    const int chunk = (N + SCAN_BLOCKS - 1) / SCAN_BLOCKS;
    const int lo = b * chunk;
    const int hi = (lo + chunk < N) ? lo + chunk : N;

    sh[t] = blockSums[t];
    __syncthreads();
    for (int off = 1; off < 256; off <<= 1) {
        int u = (t >= off) ? sh[t - off] : 0;
        __syncthreads();
        sh[t] += u;
        __syncthreads();
    }
    if (b == 0 && t == 255) rowptr[N] = sh[255];
    int carry = (b == 0) ? 0 : sh[b - 1];
    __syncthreads();

    for (int j = lo; j < hi; j += 256) {
        int i = j + t;
        int v = (i < hi) ? deg[i] : 0;
        sh[t] = v;
        __syncthreads();
        for (int off = 1; off < 256; off <<= 1) {
            int u = (t >= off) ? sh[t - off] : 0;
            __syncthreads();
            sh[t] += u;
            __syncthreads();
        }
        int excl = carry + sh[t] - v;
        if (i < hi) { rowptr[i] = excl; cursor[i] = excl; }
        carry += sh[255];
        __syncthreads();
    }
}

// ---- scatter + degree-histogram fused (both depend only on scan3b) ------
__global__ __launch_bounds__(256) void scatter_dhist_kernel(
    const int* __restrict__ ei, int E, int Etot,
    int* __restrict__ cursor, int* __restrict__ ssrc,
    const int* __restrict__ rowptr, int* __restrict__ blockHist,
    int N, int EB)
{
    if (blockIdx.x < EB) {
        int i = blockIdx.x * 256 + threadIdx.x;
        if (i >= Etot) return;
        int d, s;
        if (i < E) { s = ei[i]; d = ei[E + i]; }
        else       { s = i - E; d = s; }
        int pos = atomicAdd(&cursor[d], 1);
        ssrc[pos] = s;
    } else {
        __shared__ int lh[256];
        const int b = blockIdx.x - EB;          // 0..SORT_BLOCKS-1
        lh[threadIdx.x] = 0;
        __syncthreads();
        const int chunk = (N + SORT_BLOCKS - 1) / SORT_BLOCKS;
        const int lo = b * chunk;
        const int hi = (lo + chunk < N) ? lo + chunk : N;
        for (int d = lo + threadIdx.x; d < hi; d += 256) {
            int deg = rowptr[d + 1] - rowptr[d];
            atomicAdd(&lh[deg > 255 ? 255 : deg], 1);
        }
        __syncthreads();
        blockHist[b * 256 + threadIdx.x] = lh[threadIdx.x];
    }
}

// dscan2 folded in: each block recomputes bin totals + its own offsets.
__global__ __launch_bounds__(256) void dscatter2b_kernel(
    const int* __restrict__ rowptr, const int* __restrict__ blockHist,
    int* __restrict__ dperm, int N)
{
    __shared__ int sh[256];
    __shared__ int cur[256];
    const int b = blockIdx.x, t = threadIdx.x;

    int total = 0, myoff = 0;
    for (int bb = 0; bb < SORT_BLOCKS; ++bb) {
        int hv = blockHist[bb * 256 + t];
        if (bb < b) myoff += hv;
        total += hv;
    }
    sh[t] = total;
    __syncthreads();
    for (int off = 1; off < 256; off <<= 1) {
        int u = (t >= off) ? sh[t - off] : 0;
        __syncthreads();
        sh[t] += u;
        __syncthreads();
    }
    int grand = sh[255];
    cur[t] = (grand - sh[t]) + myoff;    // descending bin start + block offset
    __syncthreads();

    const int chunk = (N + SORT_BLOCKS - 1) / SORT_BLOCKS;
    const int lo = b * chunk;
    const int hi = (lo + chunk < N) ? lo + chunk : N;
    for (int d = lo + t; d < hi; d += 256) {
        int deg = rowptr[d + 1] - rowptr[d];
        int pos = atomicAdd(&cur[deg > 255 ? 255 : deg], 1);
        dperm[pos] = d;
    }
}

// ---------------- fused edge kernel (bf16, depth-2, XCD-head affinity) ----
// Assumes blockIdx round-robins XCDs as bid%8 (perf heuristic only).
// H=4: head = (bid&7)>>1 (2 XCDs/head); H=2: head = (bid&7)>>2 (4 XCDs/head).
template <int H, bool OUT_F32, bool OUT_BF16>
__global__ __launch_bounds__(256) void gat_fused4(
    const int* __restrict__ rowptr, const int* __restrict__ ssrc,
    const int* __restrict__ dperm,
    const unsigned short* __restrict__ xl, const unsigned short* __restrict__ xr,
    const float* __restrict__ att, const float* __restrict__ bias,
    float* __restrict__ outf, unsigned short* __restrict__ outb,
    int N, int BPH)
{
    const int bid = blockIdx.x;
    int h, j;
    if (H == 4) {
        h = (bid & 7) >> 1;
        j = ((bid >> 3) << 1) | (bid & 1);
    } else if (H == 2) {
        h = (bid & 7) >> 2;
        j = ((bid >> 3) << 2) | (bid & 3);
    } else {
        h = 0;
        j = bid;
    }
    if (j >= BPH) return;
    const int di = j * 64 + (threadIdx.x >> 2);
    const int sub = threadIdx.x & 3;
    if (di >= N) return;
    const int d  = dperm[di];
    const int HC = H * 64;
    const int so = sub * 16;

    const unsigned short* xlh = xl + (size_t)h * N * 64;

    float xrv[16], attv[16], acc[16];
    {
        const unsigned short* pr = xr + ((size_t)h * N + d) * 64 + so;
        uint4 v0 = *reinterpret_cast<const uint4*>(pr);
        uint4 v1 = *reinterpret_cast<const uint4*>(pr + 8);
        unpack8(v0, xrv); unpack8(v1, xrv + 8);
        const float* pa = att + h * 64 + so;
        #pragma unroll
        for (int k = 0; k < 16; k += 4) {
            float4 w = *reinterpret_cast<const float4*>(pa + k);
            attv[k] = w.x; attv[k+1] = w.y; attv[k+2] = w.z; attv[k+3] = w.w;
        }
    }
    #pragma unroll
    for (int k = 0; k < 16; ++k) acc[k] = 0.f;
    float M = -3.0e38f, S = 0.f;

    const int begin = rowptr[d], end = rowptr[d + 1];
    // depth-2 pipeline: (c0,c1)=data for e, (p0,p1)=e+1, loads for e+2 issued
    uint4 c0, c1, p0, p1;
    {
        const unsigned short* pl = xlh + (size_t)ssrc[begin] * 64 + so;
        c0 = *reinterpret_cast<const uint4*>(pl);
        c1 = *reinterpret_cast<const uint4*>(pl + 8);
    }
    if (begin + 1 < end) {
        const unsigned short* pl = xlh + (size_t)ssrc[begin + 1] * 64 + so;
        p0 = *reinterpret_cast<const uint4*>(pl);
        p1 = *reinterpret_cast<const uint4*>(pl + 8);
    }
    for (int e = begin; e < end; ++e) {
        uint4 q0, q1;
        const bool have2 = (e + 2 < end);
        if (have2) {
            const unsigned short* pl = xlh + (size_t)ssrc[e + 2] * 64 + so;
            q0 = *reinterpret_cast<const uint4*>(pl);
            q1 = *reinterpret_cast<const uint4*>(pl + 8);
        }
        float cur[16];
        unpack8(c0, cur);
        unpack8(c1, cur + 8);
        float p = 0.f;
        #pragma unroll
        for (int k = 0; k < 16; ++k) {
            float v = cur[k] + xrv[k];
            v = fmaxf(v, 0.2f * v);           // leaky_relu 0.2
            p = fmaf(v, attv[k], p);
        }
        p += __shfl_xor(p, 1);
        p += __shfl_xor(p, 2);
        float nM = fmaxf(M, p);
        float scale = __expf(M - nM);
        float w = __expf(p - nM);
        S = fmaf(S, scale, w);
        #pragma unroll
        for (int k = 0; k < 16; ++k) acc[k] = fmaf(acc[k], scale, w * cur[k]);
        M = nM;
        if (e + 1 < end) { c0 = p0; c1 = p1; }
        if (have2)       { p0 = q0; p1 = q1; }
    }
    float inv = 1.f / S;
    const float* pb = bias + h * 64 + so;
    #pragma unroll
    for (int k = 0; k < 16; ++k) {
        float val = fmaf(acc[k], inv, pb[k]);
        acc[k] = val > 0.f ? val : 0.f;
    }
    size_t ob = (size_t)d * HC + h * 64 + so;    // node-major output (GEMM A)
    if (OUT_F32) {
        #pragma unroll
        for (int k = 0; k < 16; k += 4) {
            float4 v = {acc[k], acc[k+1], acc[k+2], acc[k+3]};
            *reinterpret_cast<float4*>(outf + ob + k) = v;
        }
    }
    if (OUT_BF16) {
        unsigned pk[8];
        #pragma unroll
        for (int k = 0; k < 8; ++k)
            pk[k] = (unsigned)f2bf(acc[2*k]) | ((unsigned)f2bf(acc[2*k+1]) << 16);
        uint4 lo = {pk[0], pk[1], pk[2], pk[3]};
        uint4 hi = {pk[4], pk[5], pk[6], pk[7]};
        *reinterpret_cast<uint4*>(outb + ob) = lo;
        *reinterpret_cast<uint4*>(outb + ob + 8) = hi;
    }
}

// ---------------- per-graph pool + MLP (no atomics) ------------------------
__global__ __launch_bounds__(1024) void graph_pool_mlp(
    const float* __restrict__ h3, const int* __restrict__ bound,
    const float* __restrict__ Wm1, const float* __restrict__ bm1,
    const float* __restrict__ Wm2, const float* __restrict__ bm2,
    float* __restrict__ out)
{
    __shared__ float sh[1024];
    __shared__ float pooled[64];
    __shared__ float hidden[32];
    const int g = blockIdx.x;
    const int t = threadIdx.x;
    const int ch = t & 63;
    const int slot = t >> 6;              // 0..15
    const int lo = bound[g];
    const int hi = bound[g + 1];

    float acc = 0.f;
    #pragma unroll 4
    for (int n = lo + slot; n < hi; n += 16)
        acc += h3[(size_t)n * 64 + ch];
    sh[t] = acc;
    __syncthreads();
    #pragma unroll
    for (int off = 512; off >= 64; off >>= 1) {
        if (t < off) sh[t] += sh[t + off];
        __syncthreads();
    }
    if (t < 64) {
        float cnt = (float)(hi - lo);
        cnt = cnt > 1.f ? cnt : 1.f;
        pooled[t] = sh[t] / cnt;
    }
    __syncthreads();
    if (t < 32) {
        float a = bm1[t];
        #pragma unroll
        for (int k = 0; k < 64; ++k) a = fmaf(pooled[k], Wm1[k * 32 + t], a);
        hidden[t] = a > 0.f ? a : 0.f;
    }
    __syncthreads();
    if (t < 2) {
        float a = bm2[t];
        #pragma unroll
        for (int j = 0; j < 32; ++j) a = fmaf(hidden[j], Wm2[j * 2 + t], a);
        out[g * 2 + t] = a;
    }
}

// ---------------- layer driver ---------------------------------------------
static void run_layer(const unsigned short* Xb, int K, int H,
                      const float* bl, const float* br,
                      const float* att, const float* bias_out,
                      const unsigned short* Wtl, const unsigned short* Wtr,
                      const int* rowptr, const int* ssrc, const int* dperm, int N,
                      unsigned short* xl, unsigned short* xr,
                      float* houtf, unsigned short* houtb,
                      hipStream_t stream)
{
    int gblocks = (N + 63) / 64;
    if (K == 128 && H == 4)
        gemm_slab<128, 4><<<gblocks, 256, 0, stream>>>(Xb, Wtl, Wtr, bl, br, xl, xr, N);
    else if (K == 256)
        gemm_slab<256, 2><<<gblocks, 256, 0, stream>>>(Xb, Wtl, Wtr, bl, br, xl, xr, N);
    else
        gemm_slab<128, 1><<<gblocks, 256, 0, stream>>>(Xb, Wtl, Wtr, bl, br, xl, xr, N);

    int BPH = (N + 63) / 64;
    if (H == 4) {
        int grid = ((BPH * 4 + 7) / 8) * 8;
        gat_fused4<4, false, true><<<grid, 256, 0, stream>>>(
            rowptr, ssrc, dperm, xl, xr, att, bias_out, houtf, houtb, N, BPH);
    } else if (H == 2) {
        int grid = ((BPH * 2 + 7) / 8) * 8;
        gat_fused4<2, false, true><<<grid, 256, 0, stream>>>(
            rowptr, ssrc, dperm, xl, xr, att, bias_out, houtf, houtb, N, BPH);
    } else {
        gat_fused4<1, true, false><<<BPH, 256, 0, stream>>>(
            rowptr, ssrc, dperm, xl, xr, att, bias_out, houtf, houtb, N, BPH);
    }
}

extern "C" void kernel_launch(void* const* d_in, const int* in_sizes, int n_in,
                              void* d_out, int out_size, void* d_ws, size_t ws_size,
                              hipStream_t stream)
{
    const float* x    = (const float*)d_in[0];
    const int*   ei   = (const int*)d_in[1];
    const int*   batch= (const int*)d_in[2];
    const float* Wl1 = (const float*)d_in[3];
    const float* bl1 = (const float*)d_in[4];
    const float* Wr1 = (const float*)d_in[5];
    const float* br1 = (const float*)d_in[6];
    const float* att1= (const float*)d_in[7];
    const float* b1  = (const float*)d_in[8];
    const float* Wl2 = (const float*)d_in[9];
    const float* bl2 = (const float*)d_in[10];
    const float* Wr2 = (const float*)d_in[11];
    const float* br2 = (const float*)d_in[12];
    const float* att2= (const float*)d_in[13];
    const float* b2  = (const float*)d_in[14];
    const float* Wl3 = (const float*)d_in[15];
    const float* bl3 = (const float*)d_in[16];
    const float* Wr3 = (const float*)d_in[17];
    const float* br3 = (const float*)d_in[18];
    const float* att3= (const float*)d_in[19];
    const float* b3  = (const float*)d_in[20];
    const float* Wm1 = (const float*)d_in[21];
    const float* bm1 = (const float*)d_in[22];
    const float* Wm2 = (const float*)d_in[23];
    const float* bm2 = (const float*)d_in[24];

    const int N    = in_sizes[2];          // 50000
    const int E    = in_sizes[1] / 2;      // 800000
    const int Etot = E + N;                // + self loops
    const int K1   = in_sizes[0] / N;      // 128

    // workspace layout
    char* wsb = (char*)d_ws;
    size_t o = 0;
    auto alloc = [&](size_t bytes) { char* p = wsb + o; o += (bytes + 255) & ~(size_t)255; return p; };
    unsigned short* xl    = (unsigned short*)alloc((size_t)N * 256 * 2);
    unsigned short* xr    = (unsigned short*)alloc((size_t)N * 256 * 2);
    unsigned short* xb    = (unsigned short*)alloc((size_t)N * K1 * 2);
    unsigned short* h1b   = (unsigned short*)alloc((size_t)N * 256 * 2);
    unsigned short* h2b   = (unsigned short*)alloc((size_t)N * 128 * 2);
    float*          h3f   = (float*)alloc((size_t)N * 64 * 4);
    int*   deg    = (int*)alloc((size_t)N * 4);
    int*   rowptr = (int*)alloc((size_t)(N + 1) * 4);
    int*   cursor = (int*)alloc((size_t)N * 4);
    int*   ssrc   = (int*)alloc((size_t)Etot * 4);
    int*   dperm  = (int*)alloc((size_t)N * 4);
    int*   bound  = (int*)alloc(65 * 4);
    int*   blockHist = (int*)alloc((size_t)SORT_BLOCKS * 256 * 4);
    int*   blockSums = (int*)alloc((size_t)SCAN_BLOCKS * 4);
    unsigned short* Wt1l = (unsigned short*)alloc(128 * 256 * 2);
    unsigned short* Wt1r = (unsigned short*)alloc(128 * 256 * 2);
    unsigned short* Wt2l = (unsigned short*)alloc(256 * 128 * 2);
    unsigned short* Wt2r = (unsigned short*)alloc(256 * 128 * 2);
    unsigned short* Wt3l = (unsigned short*)alloc(128 * 64 * 2);
    unsigned short* Wt3r = (unsigned short*)alloc(128 * 64 * 2);
    (void)ws_size; (void)n_in; (void)out_size;

    // ---- prep: zeros + conversions + graph bounds (1 dispatch) ----
    prep_kernel<<<1024, 256, 0, stream>>>(
        x, batch, N, K1, xb,
        Wl1, Wr1, Wt1l, Wt1r, Wl2, Wr2, Wt2l, Wt2r, Wl3, Wr3, Wt3l, Wt3r,
        deg, bound);

    // ---- CSR build + degree sort (5 dispatches) ----
    hist_kernel<<<(Etot + 255) / 256, 256, 0, stream>>>(ei, E, Etot, deg);
    scan1_kernel<<<SCAN_BLOCKS, 256, 0, stream>>>(deg, blockSums, N);
    scan3b_kernel<<<SCAN_BLOCKS, 256, 0, stream>>>(deg, blockSums, rowptr, cursor, N);
    {
        int EB = (Etot + 255) / 256;
        scatter_dhist_kernel<<<EB + SORT_BLOCKS, 256, 0, stream>>>(
            ei, E, Etot, cursor, ssrc, rowptr, blockHist, N, EB);
    }
    dscatter2b_kernel<<<SORT_BLOCKS, 256, 0, stream>>>(rowptr, blockHist, dperm, N);

    // ---- layers (6 dispatches) ----
    run_layer(xb, K1, 4, bl1, br1, att1, b1, Wt1l, Wt1r,
              rowptr, ssrc, dperm, N, xl, xr, nullptr, h1b, stream);
    run_layer(h1b, 256, 2, bl2, br2, att2, b2, Wt2l, Wt2r,
              rowptr, ssrc, dperm, N, xl, xr, nullptr, h2b, stream);
    run_layer(h2b, 128, 1, bl3, br3, att3, b3, Wt3l, Wt3r,
              rowptr, ssrc, dperm, N, xl, xr, h3f, nullptr, stream);

    // ---- per-graph pool + MLP (1 dispatch) ----
    graph_pool_mlp<<<64, 1024, 0, stream>>>(
        h3f, bound, Wm1, bm1, Wm2, bm2, (float*)d_out);
}